// Round 1
// baseline (1656.816 us; speedup 1.0000x reference)
//
#include <hip/hip_runtime.h>
#include <hip/hip_bf16.h>
#include <math.h>

// Problem constants (from reference)
#define NROWS 20000
#define KDIM  9480     // T*D = 60*158
#define GEDIM 128      // G*E
#define GNUM  8
#define ENUM  16

// Router GEMM tiling
#define BM 128
#define BK 32
#define NTHREADS 256

// ---------------------------------------------------------------------------
// Kernel 1: split-K router GEMM.  partial[s][row][col] = sum over k-chunk s of
// x[row,:] . Wr[:,col]   (bias added in tail kernel).
// Two-level fp32 accumulation (per-BK chunk -> outer) for precision: top-2
// gating is discontinuous, so h must track the f64 reference to ~1e-7.
// ---------------------------------------------------------------------------
__global__ __launch_bounds__(NTHREADS, 2) void router_gemm(
    const float* __restrict__ x, const float* __restrict__ Wr,
    float* __restrict__ partial, int iters_per_chunk)
{
    __shared__ float sA[BM][BK + 4];   // +4 pad keeps float4 alignment, breaks pow2 stride
    __shared__ float sB[BK][GEDIM];

    const int tid = threadIdx.x;
    const int m0 = blockIdx.x * BM;
    const int s  = blockIdx.y;
    const int kstart = s * iters_per_chunk * BK;
    const int kend   = min(kstart + iters_per_chunk * BK, KDIM);

    const int tr = tid >> 4;      // 0..15
    const int tc = tid & 15;      // 0..15
    const int r0 = tr * 8;        // 8 rows per thread
    const int c0 = tc * 4;        // cols c0..c0+3 and c0+64..c0+67

    float acc[8][8];
#pragma unroll
    for (int i = 0; i < 8; ++i)
#pragma unroll
        for (int j = 0; j < 8; ++j) acc[i][j] = 0.f;

    for (int k0 = kstart; k0 < kend; k0 += BK) {
        // ---- stage A: 128 rows x 32 k (1024 float4, 4 per thread)
#pragma unroll
        for (int i = 0; i < 4; ++i) {
            int fid = tid + i * NTHREADS;     // 0..1023
            int r   = fid >> 3;
            int c4  = fid & 7;
            int grow = m0 + r;
            int gk   = k0 + c4 * 4;
            float4 v = make_float4(0.f, 0.f, 0.f, 0.f);
            if (grow < NROWS && gk < kend)
                v = *(const float4*)(x + (size_t)grow * KDIM + gk);
            *(float4*)&sA[r][c4 * 4] = v;
        }
        // ---- stage B: 32 k x 128 cols (1024 float4, 4 per thread)
#pragma unroll
        for (int i = 0; i < 4; ++i) {
            int fid = tid + i * NTHREADS;
            int kk  = fid >> 5;
            int c4  = fid & 31;
            int gk  = k0 + kk;
            float4 v = make_float4(0.f, 0.f, 0.f, 0.f);
            if (gk < kend)
                v = *(const float4*)(Wr + (size_t)gk * GEDIM + c4 * 4);
            *(float4*)&sB[kk][c4 * 4] = v;
        }
        __syncthreads();

        float chunk[8][8];
#pragma unroll
        for (int i = 0; i < 8; ++i)
#pragma unroll
            for (int j = 0; j < 8; ++j) chunk[i][j] = 0.f;

#pragma unroll
        for (int kq = 0; kq < BK / 4; ++kq) {
            float4 a[8];
#pragma unroll
            for (int i = 0; i < 8; ++i)
                a[i] = *(const float4*)&sA[r0 + i][kq * 4];
#pragma unroll
            for (int j = 0; j < 4; ++j) {
                int kk = kq * 4 + j;
                float4 b0 = *(const float4*)&sB[kk][c0];
                float4 b1 = *(const float4*)&sB[kk][c0 + 64];
#pragma unroll
                for (int i = 0; i < 8; ++i) {
                    float av = (j == 0) ? a[i].x : (j == 1) ? a[i].y
                             : (j == 2) ? a[i].z : a[i].w;
                    chunk[i][0] += av * b0.x;
                    chunk[i][1] += av * b0.y;
                    chunk[i][2] += av * b0.z;
                    chunk[i][3] += av * b0.w;
                    chunk[i][4] += av * b1.x;
                    chunk[i][5] += av * b1.y;
                    chunk[i][6] += av * b1.z;
                    chunk[i][7] += av * b1.w;
                }
            }
        }
#pragma unroll
        for (int i = 0; i < 8; ++i)
#pragma unroll
            for (int j = 0; j < 8; ++j) acc[i][j] += chunk[i][j];
        __syncthreads();
    }

    // ---- store partials (always store, even for empty chunks: ws is poisoned)
    float* pbase = partial + (size_t)s * NROWS * GEDIM;
#pragma unroll
    for (int i = 0; i < 8; ++i) {
        int row = m0 + r0 + i;
        if (row < NROWS) {
            float4 v0 = make_float4(acc[i][0], acc[i][1], acc[i][2], acc[i][3]);
            float4 v1 = make_float4(acc[i][4], acc[i][5], acc[i][6], acc[i][7]);
            *(float4*)(pbase + (size_t)row * GEDIM + c0)      = v0;
            *(float4*)(pbase + (size_t)row * GEDIM + c0 + 64) = v1;
        }
    }
}

// ---------------------------------------------------------------------------
// Kernel 2: per-row tail.  One wave (64 threads) per row.
// Reduce split-K partials -> h[128]; top-2 (jax tie-break: lower idx first);
// compute ONLY the <=2 selected groups' expert + attention path; gate.
// ---------------------------------------------------------------------------
__global__ __launch_bounds__(64) void tail_kernel(
    const float* __restrict__ partial, int S,
    const float* __restrict__ br,
    const float* __restrict__ We, const float* __restrict__ be,
    const float* __restrict__ Wq, const float* __restrict__ bq,
    const float* __restrict__ Wk, const float* __restrict__ bk,
    const float* __restrict__ Wv, const float* __restrict__ bv,
    const float* __restrict__ Wo, const float* __restrict__ bo,
    float* __restrict__ out)
{
    const int n    = blockIdx.x;
    const int lane = threadIdx.x;

    __shared__ float hbuf[GEDIM];
    __shared__ float eobuf[2][ENUM];
    __shared__ float qbuf[2][ENUM], kbuf[2][ENUM], vbuf[2][ENUM];
    __shared__ float abuf[2][ENUM];
    __shared__ float attbuf[2][ENUM];
    __shared__ float obuf[2];

    // 1. reduce split-K partials + bias
    float h0 = br[lane];
    float h1 = br[lane + 64];
    for (int s = 0; s < S; ++s) {
        const float* p = partial + ((size_t)s * NROWS + n) * GEDIM;
        h0 += p[lane];
        h1 += p[lane + 64];
    }
    hbuf[lane]      = h0;
    hbuf[lane + 64] = h1;

    // 2. top-2 over 128 values: butterfly merge of sorted pairs.
    //    Order: value desc, index asc on ties (matches jax.lax.top_k).
    float v1, v2; int i1, i2;
    if (h1 > h0) { v1 = h1; i1 = lane + 64; v2 = h0; i2 = lane; }
    else         { v1 = h0; i1 = lane;      v2 = h1; i2 = lane + 64; }
#pragma unroll
    for (int m = 1; m <= 32; m <<= 1) {
        float ov1 = __shfl_xor(v1, m);
        float ov2 = __shfl_xor(v2, m);
        int   oi1 = __shfl_xor(i1, m);
        int   oi2 = __shfl_xor(i2, m);
        bool a_first = (v1 > ov1) || (v1 == ov1 && i1 < oi1);
        float w1v = a_first ? v1  : ov1;  int w1i = a_first ? i1  : oi1;
        float l1v = a_first ? ov1 : v1;   int l1i = a_first ? oi1 : i1;
        float w2v = a_first ? v2  : ov2;  int w2i = a_first ? i2  : oi2;
        bool s_first = (w2v > l1v) || (w2v == l1v && w2i < l1i);
        v1 = w1v; i1 = w1i;
        v2 = s_first ? w2v : l1v;
        i2 = s_first ? w2i : l1i;
    }
    // gating weights: softmax over the two selected logits (stable form)
    float t  = expf(v2 - v1);
    float wa = 1.0f / (1.0f + t);
    float wb = 1.0f - wa;

    const int ga = i1 >> 4, fa = i1 & 15;
    const int gb = i2 >> 4, fb = i2 & 15;

    __syncthreads();   // hbuf visible

    // 3. expert outputs eo[sel][e] for the two selected groups
    {
        int e   = lane & 15;
        int sel = (lane >> 4) & 1;
        int kh  = lane >> 5;            // which half of the 128-dot
        int g   = sel ? gb : ga;
        const float* w  = We + (size_t)(g * ENUM + e) * GEDIM + kh * 64;
        const float* hp = hbuf + kh * 64;
        float acc = 0.f;
#pragma unroll
        for (int k = 0; k < 64; ++k) acc += hp[k] * w[k];
        acc += __shfl_xor(acc, 32);
        if (kh == 0) eobuf[sel][e] = acc + be[g * ENUM + e];
    }
    __syncthreads();

    // 4. Q,K,V projections (per-group 16x16, torch [out,in] layout)
    if (lane < 32) {
        int f   = lane & 15;
        int sel = lane >> 4;
        int g   = sel ? gb : ga;
        int base = (g * ENUM + f) * ENUM;
        float q = bq[g * ENUM + f];
        float k = bk[g * ENUM + f];
        float v = bv[g * ENUM + f];
#pragma unroll
        for (int e2 = 0; e2 < ENUM; ++e2) {
            float eov = eobuf[sel][e2];
            q += eov * Wq[base + e2];
            k += eov * Wk[base + e2];
            v += eov * Wv[base + e2];
        }
        qbuf[sel][f] = q;
        kbuf[sel][f] = k;
        vbuf[sel][f] = v;
    }
    __syncthreads();

    // 5. scores (head_dim is the seq axis: Qh[d][hh] = q[hh*4+d]) + softmax over e
    if (lane < 32) {
        int sel = lane >> 4;
        int d   = (lane >> 2) & 3;
        int e   = lane & 3;
        float sc = 0.f;
#pragma unroll
        for (int hh = 0; hh < 4; ++hh)
            sc += qbuf[sel][hh * 4 + d] * kbuf[sel][hh * 4 + e];
        sc *= 0.5f;   // 1/sqrt(DH), DH=4
        float mx = fmaxf(sc, __shfl_xor(sc, 1));
        mx = fmaxf(mx, __shfl_xor(mx, 2));
        float p = expf(sc - mx);
        float sum = p + __shfl_xor(p, 1);
        sum += __shfl_xor(sum, 2);
        abuf[sel][d * 4 + e] = p / sum;
    }
    __syncthreads();

    // 6. att[d][hh] = sum_e attn[d][e] * v[hh*4+e]; write back transposed to flat E
    if (lane < 32) {
        int sel = lane >> 4;
        int d   = (lane >> 2) & 3;
        int hh  = lane & 3;
        float a = 0.f;
#pragma unroll
        for (int e2 = 0; e2 < 4; ++e2)
            a += abuf[sel][d * 4 + e2] * vbuf[sel][hh * 4 + e2];
        attbuf[sel][hh * 4 + d] = a;
    }
    __syncthreads();

    // 7. only the two needed output-proj elements, then gate
    if (lane < 2) {
        int sel = lane;
        int g = sel ? gb : ga;
        int f = sel ? fb : fa;
        float o = bo[g * ENUM + f];
        int base = (g * ENUM + f) * ENUM;
#pragma unroll
        for (int e2 = 0; e2 < ENUM; ++e2)
            o += attbuf[sel][e2] * Wo[base + e2];
        obuf[sel] = o;
    }
    __syncthreads();
    if (lane == 0)
        out[n] = wa * obuf[0] + wb * obuf[1];
}

extern "C" void kernel_launch(void* const* d_in, const int* in_sizes, int n_in,
                              void* d_out, int out_size, void* d_ws, size_t ws_size,
                              hipStream_t stream)
{
    const float* x  = (const float*)d_in[0];
    const float* Wr = (const float*)d_in[1];
    const float* br = (const float*)d_in[2];
    const float* We = (const float*)d_in[3];
    const float* be = (const float*)d_in[4];
    const float* Wq = (const float*)d_in[5];
    const float* bq = (const float*)d_in[6];
    const float* Wk = (const float*)d_in[7];
    const float* bk = (const float*)d_in[8];
    const float* Wv = (const float*)d_in[9];
    const float* bv = (const float*)d_in[10];
    const float* Wo = (const float*)d_in[11];
    const float* bo = (const float*)d_in[12];
    float* out = (float*)d_out;
    float* partial = (float*)d_ws;

    // split-K factor: 8 if workspace allows (needs S * 20000*128*4 bytes)
    const size_t slice = (size_t)NROWS * GEDIM * sizeof(float);
    int S = (int)(ws_size / slice);
    if (S > 8) S = 8;
    if (S < 1) S = 1;   // (assumes ws_size >= 10.24 MB)

    const int total_iters = (KDIM + BK - 1) / BK;            // 297
    const int iters_per_chunk = (total_iters + S - 1) / S;   // 38 for S=8

    dim3 ggrid((NROWS + BM - 1) / BM, S);                    // 157 x S
    router_gemm<<<ggrid, NTHREADS, 0, stream>>>(x, Wr, partial, iters_per_chunk);

    tail_kernel<<<NROWS, 64, 0, stream>>>(partial, S, br,
                                          We, be, Wq, bq, Wk, bk, Wv, bv, Wo, bo,
                                          out);
}